// Round 6
// baseline (111.399 us; speedup 1.0000x reference)
//
#include <hip/hip_runtime.h>

// SKA: per-pixel dynamic depthwise 5x5 conv
// x: [B=8, C=256, H=64, W=64] f32
// w: [B=8, G=8, K2=25, H=64, W=64] f32
// out[b,c,h,w] = sum_k x[b,c,h+k/5-2,w+k%5-2] * w[b,g,k,h,w], g = c/32
//
// Design H5 (round 13): H4 + masking moved w-side -> x-staging-side.
// Round-12 post-mortem: H4 ~32.5us est. Throughput pipes all underused
// (DS ~21%, VALU ~13% of CU clocks; VALUBusy ~10% measured round-3) =>
// ~75% latency stall. Dominant exposure: 30 w-quads/thread from L2
// (~300cyc), and H4's MASKW cndmasks consume the prefetched loads AT
// ARRIVAL (vmcnt wait forced inside the di body to compute wn), defeating
// the double-buffer distance, plus ~250 mask VALU ops/thread.
// Change (single structural variable):
//  - OOB window rows staged as EXACT 0.0 (clamped-addr load + 4 cndmasks
//    in staging; 20 total). Col-OOB taps already read zeroed guards/pads.
//  - Weights loaded RAW, no masks. Prefetch of row di+1 feeds only next-di
//    FMAs -> compiler sinks the vmcnt wait a full iteration (~160+ clk).
//  - Bit-exact: OOB taps contribute 0*w=0 (== jnp.pad); FMA order unchanged.
// Keep from H4: PITCH=66 (b64 reads 4-way floor; PITCH=64 was 8-way 2.94x),
// __launch_bounds__(256,4) (VGPR cap 128; (256,6) forced 40 VGPR ->125MB
// scratch in round-10), one __syncthreads, NCH=4, grid 2048, chunk in slow
// blockIdx bits (w-sharing partners same XCD).
// Tripwires: VGPR 90-110 & WRITE_SIZE ~33MB (VGPR=128 or WRITE jump =>
// spill); flat dur => latency theory wrong -> next: prefetch depth 2 / NCH=8.

#define B_ 8
#define C_ 256
#define G_ 8
#define CG_ 32
#define H_ 64
#define W_ 64
#define K2_ 25
#define HW_ (H_ * W_)
#define NCH 4
#define NROWS 20            // 16-row band + 2 halo each side
#define PITCH 66            // 64 data + 2 pad words; stride ≡ 2 mod 32 banks
#define CHSTRIDE 1322       // 2 guard words + 20*66
#define LDSW (NCH * CHSTRIDE)  // 5288 words = 21.2 KB

// word(c,r,col) = c*CHSTRIDE + 2 + r*PITCH + col ; cols -2,-1 of row r land
// in row r-1's pads (r=0: channel guard words 0,1) — all zeroed below.

#define LDW(DI, Q) (*(const float4*)(wb + (size_t)((DI) * 5 + (Q)) * HW_))

__global__ __launch_bounds__(256, 4) void ska_kernel(
    const float* __restrict__ x, const float* __restrict__ w,
    float* __restrict__ out) {
  __shared__ __align__(16) float lds[LDSW];
  const int tid = threadIdx.x;
  const int lr = tid >> 4;   // output row within band (0..15)
  const int j = tid & 15;    // column quad (cols 4j..4j+3)
  const int wcol = j * 4;

  // blockIdx = [chunk(3) | b(3) | g(3) | band(2)], 2048 blocks.
  // chunk slowest: blk%8 unchanged by chunk -> w-sharing partners same XCD.
  const int blk = blockIdx.x;
  const int band = blk & 3;
  const int g = (blk >> 2) & 7;
  const int b = (blk >> 5) & 7;
  const int chunk = blk >> 8;  // 0..7

  const int h0 = band * 16;
  const int h = h0 + lr;

  // ---- zero guards (2/ch) + row pads (2 per row): 42 words x 4 ch ----
  if (tid < NCH * 42) {
    const int c = tid / 42;           // magic-mul
    const int p = tid - c * 42;
    const int word =
        (p < 2) ? p : (2 + ((p - 2) >> 1) * PITCH + 64 + ((p - 2) & 1));
    lds[c * CHSTRIDE + word] = 0.0f;
  }

  // ---- weight base; issue di=0 row RAW before staging (latency overlap) ----
  const float* wb =
      w + (size_t)(b * G_ + g) * K2_ * HW_ + (size_t)h * W_ + wcol;
  float4 wc0 = LDW(0, 0), wc1 = LDW(0, 1), wc2 = LDW(0, 2),
         wc3 = LDW(0, 3), wc4 = LDW(0, 4);

  // ---- stage x: 20 rows x 4 channels = 1280 quads = 5*256 exact ----
  // OOB window rows staged as EXACT 0 (pad semantics); clamped addr for
  // the load, cndmask to zero after.
  const size_t chan0 = (size_t)(b * C_ + g * CG_ + chunk * NCH) * HW_;
  const float* xc = x + chan0;
#pragma unroll
  for (int it = 0; it < 5; ++it) {
    const int i = tid + it * 256;
    const int c = i / 320;            // magic-mul
    const int rem = i - c * 320;
    const int rl = rem >> 4;          // window row 0..19
    const int q = rem & 15;           // column quad
    const int gr = h0 - 2 + rl;       // global row, may be OOB
    const bool rowok = (unsigned)gr < (unsigned)H_;
    const int grc = min(max(gr, 0), H_ - 1);
    float4 val = *(const float4*)(xc + (size_t)c * HW_ + grc * W_ + q * 4);
    if (!rowok) val = make_float4(0.f, 0.f, 0.f, 0.f);
    const int wo = c * CHSTRIDE + 2 + rl * PITCH + q * 4;  // 8B aligned
    *(float2*)&lds[wo] = make_float2(val.x, val.y);
    *(float2*)&lds[wo + 2] = make_float2(val.z, val.w);
  }

  __syncthreads();

  // ---- compute: di outer (raw weight row double-buffer), channels inner ----
  alignas(16) float acc[NCH][4];
#pragma unroll
  for (int c = 0; c < NCH; ++c) {
    acc[c][0] = 0.f; acc[c][1] = 0.f; acc[c][2] = 0.f; acc[c][3] = 0.f;
  }

  float4 wn0, wn1, wn2, wn3, wn4;
#pragma unroll
  for (int di = 0; di < 5; ++di) {
    if (di < 4) {  // prefetch next tap-row RAW; consumed only next di
      wn0 = LDW(di + 1, 0);
      wn1 = LDW(di + 1, 1);
      wn2 = LDW(di + 1, 2);
      wn3 = LDW(di + 1, 3);
      wn4 = LDW(di + 1, 4);
    }
    // window row R=lr+di, words a0..a0+7 = cols wcol-2..wcol+5
    const int rbase = (lr + di) * PITCH + wcol;
#pragma unroll
    for (int c = 0; c < NCH; ++c) {
      const int a0 = c * CHSTRIDE + rbase;
      alignas(16) float xr[8];
      *(float2*)&xr[0] = *(const float2*)&lds[a0];
      *(float2*)&xr[2] = *(const float2*)&lds[a0 + 2];
      *(float2*)&xr[4] = *(const float2*)&lds[a0 + 4];
      *(float2*)&xr[6] = *(const float2*)&lds[a0 + 6];
#pragma unroll
      for (int dj = 0; dj < 5; ++dj) {
        const float4 wv = (dj == 0) ? wc0
                        : (dj == 1) ? wc1
                        : (dj == 2) ? wc2
                        : (dj == 3) ? wc3
                                    : wc4;
        acc[c][0] = fmaf(xr[dj + 0], wv.x, acc[c][0]);
        acc[c][1] = fmaf(xr[dj + 1], wv.y, acc[c][1]);
        acc[c][2] = fmaf(xr[dj + 2], wv.z, acc[c][2]);
        acc[c][3] = fmaf(xr[dj + 3], wv.w, acc[c][3]);
      }
    }
    // rotate double-buffer (dead on di==4; full unroll renames)
    wc0 = wn0; wc1 = wn1; wc2 = wn2; wc3 = wn3; wc4 = wn4;
  }

  float* ob = out + chan0 + (size_t)h * W_ + wcol;
#pragma unroll
  for (int c = 0; c < NCH; ++c)
    *(float4*)(ob + (size_t)c * HW_) = *(const float4*)acc[c];
}

extern "C" void kernel_launch(void* const* d_in, const int* in_sizes, int n_in,
                              void* d_out, int out_size, void* d_ws,
                              size_t ws_size, hipStream_t stream) {
  const float* x = (const float*)d_in[0];
  const float* w = (const float*)d_in[1];
  float* out = (float*)d_out;
  // grid: 8 chunks * 8 b * 8 g * 4 bands = 2048 blocks of 256 threads
  ska_kernel<<<dim3(2048), dim3(256), 0, stream>>>(x, w, out);
}

// Round 7
// 111.106 us; speedup vs baseline: 1.0026x; 1.0026x over previous
//
#include <hip/hip_runtime.h>

// SKA: per-pixel dynamic depthwise 5x5 conv
// x: [B=8, C=256, H=64, W=64] f32
// w: [B=8, G=8, K2=25, H=64, W=64] f32
// out[b,c,h,w] = sum_k x[b,c,h+k/5-2,w+k%5-2] * w[b,g,k,h,w], g = c/32
//
// Design P (round 14): persistent-group blocks. 256 blocks (1/CU), each owns
// one (b,g,band) and loops over all 8 channel-chunks with ALL 25 w-quads
// held in VGPRs (loaded once). Double-buffered x staging in LDS.
// Round-13 post-mortem: H5 ~33us. All throughput pipes far from saturation
// (FMA floor 2.7us chip-wide, DS 4-6us, HBM floor ~15us; HBM 43% measured)
// => structural latency. Dominant term: per-chunk w re-loads from L3 (L2
// evicts w between chunk rounds: ~6MB streamed per XCD between partners),
// ~300cyc-deep di prefetch < 500-700cyc L3 latency, x8 chunks.
// This design:
//  - w loaded ONCE per block (25 float4 = 100 VGPR); zero w stalls in the
//    8-chunk steady state; w HBM traffic = 26MB exactly (was L3 re-reads).
//  - Per chunk: issue next chunk's 5 float4 x-loads -> compute current from
//    LDS buf[p] (~1700cyc >> 900cyc HBM latency) -> cndmask OOB rows to 0 ->
//    ds_write buf[1-p] -> ONE __syncthreads. (T14 issue-early/write-late.)
//  - Keep verbatim from H5: PITCH=66 (b64 4-addr/bank floor; 64 was 8-way),
//    zeroed guards/pads (both buffers, once), staged-zero OOB rows, raw
//    unmasked weights, H5 compute inner loop.
//  - __launch_bounds__(256,2): VGPR cap 256, natural ~175 (w100+acc16+
//    stage20+misc). 8 waves/CU: latency hiding comes from ILP + w-in-reg,
//    not TLP. ch-loop NOT unrolled (body ~4KB, I-cache safe); wk/acc/xr
//    indices all static inside.
// Tripwires: VGPR=256 or WRITE_SIZE >> 33MB => spill => revert to H5 shape.
// If dur >= H5 with clean counters => 2-wave ILP insufficient -> try
// NCH=8-per-chunk phases next.

#define B_ 8
#define C_ 256
#define G_ 8
#define CG_ 32
#define H_ 64
#define W_ 64
#define K2_ 25
#define HW_ (H_ * W_)
#define NCH 4               // channels per chunk
#define NCHUNK 8            // chunks per block (NCH*NCHUNK = 32 = group)
#define NROWS 20            // 16-row band + 2 halo each side
#define PITCH 66            // 64 data + 2 pad words; stride ≡ 2 mod 32 banks
#define CHSTRIDE 1322       // 2 guard words + 20*66
#define BUFW (NCH * CHSTRIDE)  // 5288 words = 21.2 KB per buffer

__global__ __launch_bounds__(256, 2) void ska_kernel(
    const float* __restrict__ x, const float* __restrict__ w,
    float* __restrict__ out) {
  __shared__ __align__(16) float lds[2 * BUFW];  // 42.3 KB
  const int tid = threadIdx.x;
  const int lr = tid >> 4;   // output row within band (0..15)
  const int j = tid & 15;    // column quad (cols 4j..4j+3)
  const int wcol = j * 4;

  // blockIdx = [b(3) | g(3) | band(2)], 256 blocks = 1 per CU.
  const int blk = blockIdx.x;
  const int band = blk & 3;
  const int g = (blk >> 2) & 7;
  const int b = blk >> 5;

  const int h0 = band * 16;
  const int h = h0 + lr;

  // ---- chunk-invariant staging slots: 5 per thread ----
  int soff[5];   // x word offset within chunk (c*HW + clamped_row*W + q*4)
  int swo[5];    // LDS word offset within buffer
  bool sok[5];   // row in bounds?
#pragma unroll
  for (int it = 0; it < 5; ++it) {
    const int i = tid + it * 256;
    const int c = i / 320;            // magic-mul
    const int rem = i - c * 320;
    const int rl = rem >> 4;          // window row 0..19
    const int q = rem & 15;           // column quad
    const int gr = h0 - 2 + rl;      // global row, may be OOB
    sok[it] = (unsigned)gr < (unsigned)H_;
    const int grc = min(max(gr, 0), H_ - 1);
    soff[it] = c * HW_ + grc * W_ + q * 4;
    swo[it] = c * CHSTRIDE + 2 + rl * PITCH + q * 4;  // 8B aligned
  }

  // ---- zero guards (2/ch) + row pads (2/row): 42 words x 4 ch, BOTH bufs ----
  if (tid < NCH * 42) {
    const int c = tid / 42;
    const int p = tid - c * 42;
    const int word =
        (p < 2) ? p : (2 + ((p - 2) >> 1) * PITCH + 64 + ((p - 2) & 1));
    lds[c * CHSTRIDE + word] = 0.0f;
    lds[BUFW + c * CHSTRIDE + word] = 0.0f;
  }

  // ---- issue chunk-0 x loads FIRST (so ds_write need not wait for w) ----
  const size_t gbase = (size_t)(b * C_ + g * CG_) * HW_;
  const float* xg = x + gbase;
  float4 s0 = *(const float4*)(xg + soff[0]);
  float4 s1 = *(const float4*)(xg + soff[1]);
  float4 s2 = *(const float4*)(xg + soff[2]);
  float4 s3 = *(const float4*)(xg + soff[3]);
  float4 s4 = *(const float4*)(xg + soff[4]);

  // ---- load ALL 25 weight quads RAW, once (held in VGPRs all kernel) ----
  const float* wb =
      w + (size_t)(b * G_ + g) * K2_ * HW_ + (size_t)h * W_ + wcol;
  float4 wk[K2_];
#pragma unroll
  for (int k = 0; k < K2_; ++k)
    wk[k] = *(const float4*)(wb + (size_t)k * HW_);

  // ---- write chunk 0 to buf 0 (OOB rows as exact 0 = jnp.pad) ----
  {
    float4 v0 = sok[0] ? s0 : make_float4(0.f, 0.f, 0.f, 0.f);
    float4 v1 = sok[1] ? s1 : make_float4(0.f, 0.f, 0.f, 0.f);
    float4 v2 = sok[2] ? s2 : make_float4(0.f, 0.f, 0.f, 0.f);
    float4 v3 = sok[3] ? s3 : make_float4(0.f, 0.f, 0.f, 0.f);
    float4 v4 = sok[4] ? s4 : make_float4(0.f, 0.f, 0.f, 0.f);
    *(float2*)&lds[swo[0]] = make_float2(v0.x, v0.y);
    *(float2*)&lds[swo[0] + 2] = make_float2(v0.z, v0.w);
    *(float2*)&lds[swo[1]] = make_float2(v1.x, v1.y);
    *(float2*)&lds[swo[1] + 2] = make_float2(v1.z, v1.w);
    *(float2*)&lds[swo[2]] = make_float2(v2.x, v2.y);
    *(float2*)&lds[swo[2] + 2] = make_float2(v2.z, v2.w);
    *(float2*)&lds[swo[3]] = make_float2(v3.x, v3.y);
    *(float2*)&lds[swo[3] + 2] = make_float2(v3.z, v3.w);
    *(float2*)&lds[swo[4]] = make_float2(v4.x, v4.y);
    *(float2*)&lds[swo[4] + 2] = make_float2(v4.z, v4.w);
  }
  __syncthreads();

  float* og = out + gbase + (size_t)h * W_ + wcol;

  // ---- 8-chunk steady-state loop (NOT unrolled; body ~4KB) ----
  for (int ch = 0; ch < NCHUNK; ++ch) {
    const int p = ch & 1;

    // issue next chunk's x loads; consumed only at ds_write after compute
    if (ch < NCHUNK - 1) {
      const float* xn = xg + (size_t)(ch + 1) * NCH * HW_;
      s0 = *(const float4*)(xn + soff[0]);
      s1 = *(const float4*)(xn + soff[1]);
      s2 = *(const float4*)(xn + soff[2]);
      s3 = *(const float4*)(xn + soff[3]);
      s4 = *(const float4*)(xn + soff[4]);
    }

    // ---- compute chunk ch from buf[p] (H5 inner loop, w from regs) ----
    alignas(16) float acc[NCH][4];
#pragma unroll
    for (int c = 0; c < NCH; ++c) {
      acc[c][0] = 0.f; acc[c][1] = 0.f; acc[c][2] = 0.f; acc[c][3] = 0.f;
    }
    const int pb = p * BUFW;
#pragma unroll
    for (int di = 0; di < 5; ++di) {
      // window row R=lr+di, words a0..a0+7 = cols wcol-2..wcol+5
      const int rbase = pb + (lr + di) * PITCH + wcol;
#pragma unroll
      for (int c = 0; c < NCH; ++c) {
        const int a0 = c * CHSTRIDE + rbase;
        alignas(16) float xr[8];
        *(float2*)&xr[0] = *(const float2*)&lds[a0];
        *(float2*)&xr[2] = *(const float2*)&lds[a0 + 2];
        *(float2*)&xr[4] = *(const float2*)&lds[a0 + 4];
        *(float2*)&xr[6] = *(const float2*)&lds[a0 + 6];
#pragma unroll
        for (int dj = 0; dj < 5; ++dj) {
          const float4 wv = wk[di * 5 + dj];  // static index after unroll
          acc[c][0] = fmaf(xr[dj + 0], wv.x, acc[c][0]);
          acc[c][1] = fmaf(xr[dj + 1], wv.y, acc[c][1]);
          acc[c][2] = fmaf(xr[dj + 2], wv.z, acc[c][2]);
          acc[c][3] = fmaf(xr[dj + 3], wv.w, acc[c][3]);
        }
      }
    }

    // ---- store chunk ch outputs ----
    float* ob = og + (size_t)ch * NCH * HW_;
    *(float4*)(ob + (size_t)0 * HW_) = *(const float4*)acc[0];
    *(float4*)(ob + (size_t)1 * HW_) = *(const float4*)acc[1];
    *(float4*)(ob + (size_t)2 * HW_) = *(const float4*)acc[2];
    *(float4*)(ob + (size_t)3 * HW_) = *(const float4*)acc[3];

    // ---- write next chunk to buf[1-p]; one barrier per chunk ----
    if (ch < NCHUNK - 1) {
      const int ob2 = (1 - p) * BUFW;
      float4 v0 = sok[0] ? s0 : make_float4(0.f, 0.f, 0.f, 0.f);
      float4 v1 = sok[1] ? s1 : make_float4(0.f, 0.f, 0.f, 0.f);
      float4 v2 = sok[2] ? s2 : make_float4(0.f, 0.f, 0.f, 0.f);
      float4 v3 = sok[3] ? s3 : make_float4(0.f, 0.f, 0.f, 0.f);
      float4 v4 = sok[4] ? s4 : make_float4(0.f, 0.f, 0.f, 0.f);
      *(float2*)&lds[ob2 + swo[0]] = make_float2(v0.x, v0.y);
      *(float2*)&lds[ob2 + swo[0] + 2] = make_float2(v0.z, v0.w);
      *(float2*)&lds[ob2 + swo[1]] = make_float2(v1.x, v1.y);
      *(float2*)&lds[ob2 + swo[1] + 2] = make_float2(v1.z, v1.w);
      *(float2*)&lds[ob2 + swo[2]] = make_float2(v2.x, v2.y);
      *(float2*)&lds[ob2 + swo[2] + 2] = make_float2(v2.z, v2.w);
      *(float2*)&lds[ob2 + swo[3]] = make_float2(v3.x, v3.y);
      *(float2*)&lds[ob2 + swo[3] + 2] = make_float2(v3.z, v3.w);
      *(float2*)&lds[ob2 + swo[4]] = make_float2(v4.x, v4.y);
      *(float2*)&lds[ob2 + swo[4] + 2] = make_float2(v4.z, v4.w);
      __syncthreads();
    }
  }
}

extern "C" void kernel_launch(void* const* d_in, const int* in_sizes, int n_in,
                              void* d_out, int out_size, void* d_ws,
                              size_t ws_size, hipStream_t stream) {
  const float* x = (const float*)d_in[0];
  const float* w = (const float*)d_in[1];
  float* out = (float*)d_out;
  // grid: 8 b * 8 g * 4 bands = 256 blocks of 256 threads (1 per CU)
  ska_kernel<<<dim3(256), dim3(256), 0, stream>>>(x, w, out);
}

// Round 8
// 104.621 us; speedup vs baseline: 1.0648x; 1.0620x over previous
//
#include <hip/hip_runtime.h>

// SKA: per-pixel dynamic depthwise 5x5 conv
// x: [B=8, C=256, H=64, W=64] f32
// w: [B=8, G=8, K2=25, H=64, W=64] f32
// out[b,c,h,w] = sum_k x[b,c,h+k/5-2,w+k%5-2] * w[b,g,k,h,w], g = c/32
//
// Design P2 (round 15): P + memory-level-parallelism fix.
// Round-14 post-mortem: P (w fully in VGPRs, 1 block/CU) == H5 == H4 ~33us.
// All pipes underused (FMA 3us, DS 3-8us, HBM floor 16us) yet HBM stuck at
// ~43-50%. Little's law: 6.3TB/s x 900ns needs ~22KB in flight PER CU
// continuously. P issues 20KB once per ~2400cyc chunk, in flight only
// ~900cyc => duty 37% => ~3TB/s. That is the shared ceiling of H3/H4/H5/P.
// Fixes (structure kept from P):
//  - 2-deep chunk prefetch: two reg sets rA/rB; during compute(i), loads for
//    i+1 AND i+2 are in flight (20-40KB/block continuous). LDS still double-
//    buffered: data lands in LDS one chunk before use, TWO chunks after
//    issue -> ds_write's vmcnt wait ~free.
//  - 2 blocks/CU (grid 512, each block = half group = 4 chunks of NCH=4):
//    one block's memory-idle gaps covered by the other. 8 waves/CU.
//    LDS 2 x 41.3KB = 82.6KB <= 160 OK. half bit slowest in blockIdx ->
//    w-sharing partners (stride 256 = 0 mod 8) stay on one XCD.
//  - Output stores AFTER the barrier: pre-ds_write vmcnt(0) no longer
//    drains them (they fly during next chunk's compute).
//  - 4-chunk loop fully unrolled: rA/rB rotation + LDS bases all static.
// Keep: PITCH=66 (b64 reads at 4-addr/bank floor; 64 was 8-way 2.94x),
// staged-zero OOB rows (exact jnp.pad semantics), raw unmasked w in VGPRs
// (loaded once), zeroed guards/pads, one barrier per chunk.
// Tripwires: VGPR ~190-215 target; if ska APPEARS in top-5 (>42us) it
// spilled (WRITE_SIZE >> 33MB) -> fallback: drop rB (1-deep prefetch).

#define B_ 8
#define C_ 256
#define G_ 8
#define CG_ 32
#define H_ 64
#define W_ 64
#define K2_ 25
#define HW_ (H_ * W_)
#define NCH 4               // channels per chunk
#define NCHUNK 4            // chunks per block (half group = 16 channels)
#define NROWS 20            // 16-row band + 2 halo each side
#define PITCH 66            // 64 data + 2 pad words; stride == 2 mod 32 banks
#define CHSTRIDE 1322       // 2 guard words + 20*66
#define BUFW (NCH * CHSTRIDE)  // 5288 words = 21.2 KB per buffer

#define ISSUE(R0, R1, R2, R3, R4, CH)                    \
  {                                                      \
    const float* xn = xg + (size_t)(CH) * NCH * HW_;     \
    R0 = *(const float4*)(xn + soff[0]);                 \
    R1 = *(const float4*)(xn + soff[1]);                 \
    R2 = *(const float4*)(xn + soff[2]);                 \
    R3 = *(const float4*)(xn + soff[3]);                 \
    R4 = *(const float4*)(xn + soff[4]);                 \
  }

// OOB rows staged as exact 0 (= jnp.pad); cndmask consumes loads right at
// the ds_write, which is where the vmcnt wait belongs anyway.
#define STAGE(R0, R1, R2, R3, R4, PB)                                     \
  {                                                                       \
    const float4 z4 = make_float4(0.f, 0.f, 0.f, 0.f);                    \
    const float4 v0 = sok[0] ? R0 : z4;                                   \
    const float4 v1 = sok[1] ? R1 : z4;                                   \
    const float4 v2 = sok[2] ? R2 : z4;                                   \
    const float4 v3 = sok[3] ? R3 : z4;                                   \
    const float4 v4 = sok[4] ? R4 : z4;                                   \
    *(float2*)&lds[(PB) + swo[0]] = make_float2(v0.x, v0.y);              \
    *(float2*)&lds[(PB) + swo[0] + 2] = make_float2(v0.z, v0.w);          \
    *(float2*)&lds[(PB) + swo[1]] = make_float2(v1.x, v1.y);              \
    *(float2*)&lds[(PB) + swo[1] + 2] = make_float2(v1.z, v1.w);          \
    *(float2*)&lds[(PB) + swo[2]] = make_float2(v2.x, v2.y);              \
    *(float2*)&lds[(PB) + swo[2] + 2] = make_float2(v2.z, v2.w);          \
    *(float2*)&lds[(PB) + swo[3]] = make_float2(v3.x, v3.y);              \
    *(float2*)&lds[(PB) + swo[3] + 2] = make_float2(v3.z, v3.w);          \
    *(float2*)&lds[(PB) + swo[4]] = make_float2(v4.x, v4.y);              \
    *(float2*)&lds[(PB) + swo[4] + 2] = make_float2(v4.z, v4.w);          \
  }

// compute NCH channel quads from buf at word offset PB into acc[][]
#define COMPUTE(PB)                                                       \
  _Pragma("unroll") for (int c = 0; c < NCH; ++c) {                       \
    acc[c][0] = 0.f; acc[c][1] = 0.f; acc[c][2] = 0.f; acc[c][3] = 0.f;   \
  }                                                                       \
  _Pragma("unroll") for (int di = 0; di < 5; ++di) {                      \
    const int rbase = (PB) + (lr + di) * PITCH + wcol;                    \
    _Pragma("unroll") for (int c = 0; c < NCH; ++c) {                     \
      const int a0 = c * CHSTRIDE + rbase;                                \
      alignas(16) float xr[8];                                            \
      *(float2*)&xr[0] = *(const float2*)&lds[a0];                        \
      *(float2*)&xr[2] = *(const float2*)&lds[a0 + 2];                    \
      *(float2*)&xr[4] = *(const float2*)&lds[a0 + 4];                    \
      *(float2*)&xr[6] = *(const float2*)&lds[a0 + 6];                    \
      _Pragma("unroll") for (int dj = 0; dj < 5; ++dj) {                  \
        const float4 wv = wk[di * 5 + dj];                                \
        acc[c][0] = fmaf(xr[dj + 0], wv.x, acc[c][0]);                    \
        acc[c][1] = fmaf(xr[dj + 1], wv.y, acc[c][1]);                    \
        acc[c][2] = fmaf(xr[dj + 2], wv.z, acc[c][2]);                    \
        acc[c][3] = fmaf(xr[dj + 3], wv.w, acc[c][3]);                    \
      }                                                                   \
    }                                                                     \
  }

#define STORE(CH)                                                         \
  {                                                                       \
    float* ob = og + (size_t)(CH) * NCH * HW_;                            \
    *(float4*)(ob + (size_t)0 * HW_) = *(const float4*)acc[0];            \
    *(float4*)(ob + (size_t)1 * HW_) = *(const float4*)acc[1];            \
    *(float4*)(ob + (size_t)2 * HW_) = *(const float4*)acc[2];            \
    *(float4*)(ob + (size_t)3 * HW_) = *(const float4*)acc[3];            \
  }

__global__ __launch_bounds__(256, 2) void ska_kernel(
    const float* __restrict__ x, const float* __restrict__ w,
    float* __restrict__ out) {
  __shared__ __align__(16) float lds[2 * BUFW];  // 41.3 KB
  const int tid = threadIdx.x;
  const int lr = tid >> 4;   // output row within band (0..15)
  const int j = tid & 15;    // column quad (cols 4j..4j+3)
  const int wcol = j * 4;

  // blockIdx = [half(1) | b(3) | g(3) | band(2)], 512 blocks = 2 per CU.
  const int blk = blockIdx.x;
  const int band = blk & 3;
  const int g = (blk >> 2) & 7;
  const int b = (blk >> 5) & 7;
  const int half = blk >> 8;  // 0/1: which 16 channels of the group

  const int h0 = band * 16;
  const int h = h0 + lr;

  // ---- chunk-invariant staging slots: 5 per thread ----
  int soff[5];   // x word offset within chunk (c*HW + clamped_row*W + q*4)
  int swo[5];    // LDS word offset within buffer
  bool sok[5];   // row in bounds?
#pragma unroll
  for (int it = 0; it < 5; ++it) {
    const int i = tid + it * 256;
    const int c = i / 320;            // magic-mul
    const int rem = i - c * 320;
    const int rl = rem >> 4;          // window row 0..19
    const int q = rem & 15;           // column quad
    const int gr = h0 - 2 + rl;       // global row, may be OOB
    sok[it] = (unsigned)gr < (unsigned)H_;
    const int grc = min(max(gr, 0), H_ - 1);
    soff[it] = c * HW_ + grc * W_ + q * 4;
    swo[it] = c * CHSTRIDE + 2 + rl * PITCH + q * 4;  // 8B aligned
  }

  // ---- zero guards (2/ch) + row pads (2/row): 42 words x 4 ch, BOTH bufs ----
  if (tid < NCH * 42) {
    const int c = tid / 42;
    const int p = tid - c * 42;
    const int word =
        (p < 2) ? p : (2 + ((p - 2) >> 1) * PITCH + 64 + ((p - 2) & 1));
    lds[c * CHSTRIDE + word] = 0.0f;
    lds[BUFW + c * CHSTRIDE + word] = 0.0f;
  }

  const size_t chanbase = (size_t)(b * C_ + g * CG_ + half * 16) * HW_;
  const float* xg = x + chanbase;
  float* og = out + chanbase + (size_t)h * W_ + wcol;

  // ---- prologue: issue chunk 0 AND chunk 1 loads (2-deep from the start) ----
  float4 a0, a1, a2, a3, a4;   // reg set A
  float4 b0, b1, b2, b3, b4;   // reg set B
  ISSUE(a0, a1, a2, a3, a4, 0)
  ISSUE(b0, b1, b2, b3, b4, 1)

  // ---- load ALL 25 weight quads RAW, once (VGPR-resident all kernel) ----
  const float* wb =
      w + (size_t)(b * G_ + g) * K2_ * HW_ + (size_t)h * W_ + wcol;
  float4 wk[K2_];
#pragma unroll
  for (int k = 0; k < K2_; ++k)
    wk[k] = *(const float4*)(wb + (size_t)k * HW_);

  STAGE(a0, a1, a2, a3, a4, 0)   // chunk 0 -> buf0 (waits only chunk-0 loads)
  __syncthreads();

  alignas(16) float acc[NCH][4];

  // ---- chunk 0: issue L2 into A; compute buf0; stage chunk1 -> buf1 ----
  ISSUE(a0, a1, a2, a3, a4, 2)
  COMPUTE(0)
  STAGE(b0, b1, b2, b3, b4, BUFW)
  __syncthreads();
  STORE(0)

  // ---- chunk 1: issue L3 into B; compute buf1; stage chunk2 -> buf0 ----
  ISSUE(b0, b1, b2, b3, b4, 3)
  COMPUTE(BUFW)
  STAGE(a0, a1, a2, a3, a4, 0)
  __syncthreads();
  STORE(1)

  // ---- chunk 2: compute buf0; stage chunk3 -> buf1 ----
  COMPUTE(0)
  STAGE(b0, b1, b2, b3, b4, BUFW)
  __syncthreads();
  STORE(2)

  // ---- chunk 3: compute buf1; store ----
  COMPUTE(BUFW)
  STORE(3)
}

extern "C" void kernel_launch(void* const* d_in, const int* in_sizes, int n_in,
                              void* d_out, int out_size, void* d_ws,
                              size_t ws_size, hipStream_t stream) {
  const float* x = (const float*)d_in[0];
  const float* w = (const float*)d_in[1];
  float* out = (float*)d_out;
  // grid: 2 halves * 8 b * 8 g * 4 bands = 512 blocks of 256 threads
  ska_kernel<<<dim3(512), dim3(256), 0, stream>>>(x, w, out);
}